// Round 1
// baseline (65692.627 us; speedup 1.0000x reference)
//
#include <hip/hip_runtime.h>
#include <math.h>

#define T_SEQ 256
#define BATCH 16

// ---------------- embedding gather ----------------
__global__ __launch_bounds__(256) void embed_kernel(const int* __restrict__ tok,
                                                    const float* __restrict__ emb,
                                                    float* __restrict__ x, int D) {
  int row = blockIdx.x;                 // b*T + t, 0..4095
  int tk = tok[row];
  const float* src = emb + (size_t)tk * D;
  float* dst = x + (size_t)row * D;
  for (int d = threadIdx.x; d < D; d += blockDim.x) dst[d] = src[d];
}

// ---------------- generic fp32 GEMM: C[M,N] = A[M,K] @ B[K,N] + bias ----------------
#define BM 64
#define BN 64
#define BK 16
__global__ __launch_bounds__(256) void gemm_bias(const float* __restrict__ A,
                                                 const float* __restrict__ B,
                                                 const float* __restrict__ bias,
                                                 float* __restrict__ C,
                                                 int M, int N, int K) {
  __shared__ float As[BK][BM + 1];
  __shared__ float Bs[BK][BN];
  int row0 = blockIdx.y * BM;
  int col0 = blockIdx.x * BN;
  int tid = threadIdx.x;
  int tx = tid & 15, ty = tid >> 4;     // 16x16 thread grid, 4x4 per thread
  float acc[4][4] = {};
  for (int k0 = 0; k0 < K; k0 += BK) {
    {   // A tile: 64 rows x 16 k   (lane-contiguous in k: 64B segments)
      int kk = tid & 15;
      int m0 = tid >> 4;
      #pragma unroll
      for (int r = 0; r < 4; ++r) {
        int m = m0 + 16 * r;
        int k = k0 + kk;
        float v = 0.f;
        if (k < K) v = A[(size_t)(row0 + m) * K + k];
        As[kk][m] = v;
      }
    }
    {   // B tile: 16 k x 64 n  (lane-contiguous in n)
      int n = tid & 63;
      int kk0 = tid >> 6;
      #pragma unroll
      for (int r = 0; r < 4; ++r) {
        int kk = kk0 + 4 * r;
        int k = k0 + kk;
        int ng = col0 + n;
        float v = 0.f;
        if (k < K && ng < N) v = B[(size_t)k * N + ng];
        Bs[kk][n] = v;
      }
    }
    __syncthreads();
    #pragma unroll
    for (int kk = 0; kk < BK; ++kk) {
      float a[4], b[4];
      #pragma unroll
      for (int i = 0; i < 4; ++i) a[i] = As[kk][ty * 4 + i];
      #pragma unroll
      for (int j = 0; j < 4; ++j) b[j] = Bs[kk][tx * 4 + j];
      #pragma unroll
      for (int i = 0; i < 4; ++i)
        #pragma unroll
        for (int j = 0; j < 4; ++j) acc[i][j] += a[i] * b[j];
    }
    __syncthreads();
  }
  #pragma unroll
  for (int i = 0; i < 4; ++i) {
    int m = row0 + ty * 4 + i;          // M=4096 always divisible by 64
    #pragma unroll
    for (int j = 0; j < 4; ++j) {
      int n = col0 + tx * 4 + j;
      if (n < N) {
        float v = acc[i][j];
        if (bias) v += bias[n];
        C[(size_t)m * N + n] = v;
      }
    }
  }
}

// ---------------- decode GEMM: C[M,N] = A[M,K] @ B[N,K]^T  (B = emb) ----------------
__global__ __launch_bounds__(256) void gemm_bt(const float* __restrict__ A,
                                               const float* __restrict__ B,
                                               float* __restrict__ C,
                                               int M, int N, int K) {
  __shared__ float As[BK][BM + 1];
  __shared__ float Bs[BK][BN + 1];
  int row0 = blockIdx.y * BM;
  int col0 = blockIdx.x * BN;
  int tid = threadIdx.x;
  int tx = tid & 15, ty = tid >> 4;
  float acc[4][4] = {};
  for (int k0 = 0; k0 < K; k0 += BK) {
    {
      int kk = tid & 15;
      int m0 = tid >> 4;
      #pragma unroll
      for (int r = 0; r < 4; ++r) {
        int m = m0 + 16 * r;
        int k = k0 + kk;
        float v = 0.f;
        if (k < K) v = A[(size_t)(row0 + m) * K + k];
        As[kk][m] = v;
      }
    }
    {   // Bs[kk][n] = B[(col0+n)*K + k0+kk]  (lane-contiguous in k within an emb row)
      int kk = tid & 15;
      int n0 = tid >> 4;
      #pragma unroll
      for (int r = 0; r < 4; ++r) {
        int n = n0 + 16 * r;
        int ng = col0 + n;
        int k = k0 + kk;
        float v = 0.f;
        if (ng < N && k < K) v = B[(size_t)ng * K + k];
        Bs[kk][n] = v;
      }
    }
    __syncthreads();
    #pragma unroll
    for (int kk = 0; kk < BK; ++kk) {
      float a[4], b[4];
      #pragma unroll
      for (int i = 0; i < 4; ++i) a[i] = As[kk][ty * 4 + i];
      #pragma unroll
      for (int j = 0; j < 4; ++j) b[j] = Bs[kk][tx * 4 + j];
      #pragma unroll
      for (int i = 0; i < 4; ++i)
        #pragma unroll
        for (int j = 0; j < 4; ++j) acc[i][j] += a[i] * b[j];
    }
    __syncthreads();
  }
  #pragma unroll
  for (int i = 0; i < 4; ++i) {
    int m = row0 + ty * 4 + i;
    #pragma unroll
    for (int j = 0; j < 4; ++j) {
      int n = col0 + tx * 4 + j;
      if (n < N) C[(size_t)m * N + n] = acc[i][j];
    }
  }
}

// ---------------- LSTM one timestep ----------------
// Block owns 16 hidden units (all 4 gate columns of each) -> can do the full
// gate nonlinearity + c/h update locally. c state is private to the owning
// block across steps (same blockIdx each launch). h double-buffered in ws.
// 256 threads = 4 waves; wave w handles batches 4w..4w+3; lane = gate*16+unit.
__global__ __launch_bounds__(256) void lstm_step(const float* __restrict__ xg,
                                                 const float* __restrict__ Um,
                                                 const float* __restrict__ h_in,
                                                 float* __restrict__ h_out,
                                                 float* __restrict__ c_st,
                                                 float* __restrict__ h_all,
                                                 int UNITS, int t) {
  const int N = 4 * UNITS;
  int lane = threadIdx.x & 63;
  int w = threadIdx.x >> 6;            // 0..3
  int g = lane >> 4;                   // gate 0..3 (i,f,c,o)
  int ii = lane & 15;
  int j = blockIdx.x * 16 + ii;        // hidden unit
  bool valid = (j < UNITS);
  int col = g * UNITS + j;

  float acc0 = 0.f, acc1 = 0.f, acc2 = 0.f, acc3 = 0.f;
  if (valid) {
    const float* h0 = h_in + (size_t)(4 * w + 0) * UNITS;
    const float* h1 = h_in + (size_t)(4 * w + 1) * UNITS;
    const float* h2 = h_in + (size_t)(4 * w + 2) * UNITS;
    const float* h3 = h_in + (size_t)(4 * w + 3) * UNITS;
    int k = 0;
    // b*UNITS is even (1150, 400 both even) -> float2 (8B) aligned
    for (; k + 4 <= UNITS; k += 4) {
      float2 a01 = *(const float2*)(h0 + k);
      float2 a23 = *(const float2*)(h0 + k + 2);
      float2 b01 = *(const float2*)(h1 + k);
      float2 b23 = *(const float2*)(h1 + k + 2);
      float2 c01 = *(const float2*)(h2 + k);
      float2 c23 = *(const float2*)(h2 + k + 2);
      float2 d01 = *(const float2*)(h3 + k);
      float2 d23 = *(const float2*)(h3 + k + 2);
      float u0 = Um[(size_t)(k + 0) * N + col];
      float u1 = Um[(size_t)(k + 1) * N + col];
      float u2 = Um[(size_t)(k + 2) * N + col];
      float u3 = Um[(size_t)(k + 3) * N + col];
      acc0 += a01.x * u0 + a01.y * u1 + a23.x * u2 + a23.y * u3;
      acc1 += b01.x * u0 + b01.y * u1 + b23.x * u2 + b23.y * u3;
      acc2 += c01.x * u0 + c01.y * u1 + c23.x * u2 + c23.y * u3;
      acc3 += d01.x * u0 + d01.y * u1 + d23.x * u2 + d23.y * u3;
    }
    for (; k < UNITS; ++k) {
      float u0 = Um[(size_t)k * N + col];
      acc0 += h0[k] * u0;
      acc1 += h1[k] * u0;
      acc2 += h2[k] * u0;
      acc3 += h3[k] * u0;
    }
  }

  __shared__ float gls[BATCH][64];     // [batch][gate*16+unit] pre-activations
  if (valid) {
    int b0 = 4 * w;
    gls[b0 + 0][lane] = acc0 + xg[((size_t)(b0 + 0) * T_SEQ + t) * N + col];
    gls[b0 + 1][lane] = acc1 + xg[((size_t)(b0 + 1) * T_SEQ + t) * N + col];
    gls[b0 + 2][lane] = acc2 + xg[((size_t)(b0 + 2) * T_SEQ + t) * N + col];
    gls[b0 + 3][lane] = acc3 + xg[((size_t)(b0 + 3) * T_SEQ + t) * N + col];
  }
  __syncthreads();

  // update phase: 256 threads = 16 batches x 16 units
  int ub = threadIdx.x >> 4;
  int ui = threadIdx.x & 15;
  int uj = blockIdx.x * 16 + ui;
  if (uj < UNITS) {
    float gi = gls[ub][0 * 16 + ui];
    float gf = gls[ub][1 * 16 + ui];
    float gc = gls[ub][2 * 16 + ui];
    float go = gls[ub][3 * 16 + ui];
    float si = 1.f / (1.f + expf(-gi));
    float sf = 1.f / (1.f + expf(-gf));
    float so = 1.f / (1.f + expf(-go));
    float tc = tanhf(gc);
    size_t cidx = (size_t)ub * UNITS + uj;
    float c = sf * c_st[cidx] + si * tc;
    c_st[cidx] = c;
    float h = so * tanhf(c);
    h_out[cidx] = h;
    h_all[((size_t)ub * T_SEQ + t) * UNITS + uj] = h;
  }
}

// ---------------- in-place row softmax ----------------
__global__ __launch_bounds__(256) void softmax_kernel(float* __restrict__ out, int N) {
  size_t row = blockIdx.x;
  float* p = out + row * (size_t)N;
  __shared__ float sred[8];

  float m = -INFINITY;
  for (int i = threadIdx.x; i < N; i += 256) m = fmaxf(m, p[i]);
  #pragma unroll
  for (int off = 32; off > 0; off >>= 1) m = fmaxf(m, __shfl_down(m, off, 64));
  if ((threadIdx.x & 63) == 0) sred[threadIdx.x >> 6] = m;
  __syncthreads();
  m = fmaxf(fmaxf(sred[0], sred[1]), fmaxf(sred[2], sred[3]));
  __syncthreads();

  float s = 0.f;
  for (int i = threadIdx.x; i < N; i += 256) s += expf(p[i] - m);
  #pragma unroll
  for (int off = 32; off > 0; off >>= 1) s += __shfl_down(s, off, 64);
  if ((threadIdx.x & 63) == 0) sred[4 + (threadIdx.x >> 6)] = s;
  __syncthreads();
  s = (sred[4] + sred[5]) + (sred[6] + sred[7]);
  float inv = 1.f / s;
  for (int i = threadIdx.x; i < N; i += 256) p[i] = expf(p[i] - m) * inv;
}

// ---------------- launcher ----------------
extern "C" void kernel_launch(void* const* d_in, const int* in_sizes, int n_in,
                              void* d_out, int out_size, void* d_ws, size_t ws_size,
                              hipStream_t stream) {
  const int* tok  = (const int*)d_in[0];
  const float* emb = (const float*)d_in[1];
  const float* W0 = (const float*)d_in[2];
  const float* U0 = (const float*)d_in[3];
  const float* b0 = (const float*)d_in[4];
  const float* W1 = (const float*)d_in[5];
  const float* U1 = (const float*)d_in[6];
  const float* b1 = (const float*)d_in[7];
  const float* W2 = (const float*)d_in[8];
  const float* U2 = (const float*)d_in[9];
  const float* b2 = (const float*)d_in[10];
  float* out = (float*)d_out;
  float* ws = (float*)d_ws;

  const int M = BATCH * T_SEQ;         // 4096
  const int NHID = 1150, NINP = 400, V = 33279;

  // ws layout (floats): ~120.5 MiB total
  float* x0   = ws;                          // 4096*400
  float* xg   = x0 + (size_t)M * NINP;       // 4096*4600 (reused per layer)
  float* hA   = xg + (size_t)M * 4 * NHID;   // 4096*1150
  float* hB   = hA + (size_t)M * NHID;       // 4096*1150
  float* hC   = hB + (size_t)M * NHID;       // 4096*400
  float* hbuf = hC + (size_t)M * NINP;       // 2*16*1150 (double buffer)
  float* cbuf = hbuf + 2 * (size_t)BATCH * NHID; // 16*1150

  const size_t stateBytes = (2 * (size_t)BATCH * NHID + (size_t)BATCH * NHID) * sizeof(float);

  embed_kernel<<<M, 256, 0, stream>>>(tok, emb, x0, NINP);

  // ---- layer 0: 400 -> 1150 ----
  gemm_bias<<<dim3((4 * NHID + BN - 1) / BN, M / BM), 256, 0, stream>>>(
      x0, W0, b0, xg, M, 4 * NHID, NINP);
  hipMemsetAsync(hbuf, 0, stateBytes, stream);
  for (int t = 0; t < T_SEQ; ++t) {
    lstm_step<<<(NHID + 15) / 16, 256, 0, stream>>>(
        xg, U0, hbuf + (size_t)(t & 1) * BATCH * NHID,
        hbuf + (size_t)((t + 1) & 1) * BATCH * NHID, cbuf, hA, NHID, t);
  }

  // ---- layer 1: 1150 -> 1150 ----
  gemm_bias<<<dim3((4 * NHID + BN - 1) / BN, M / BM), 256, 0, stream>>>(
      hA, W1, b1, xg, M, 4 * NHID, NHID);
  hipMemsetAsync(hbuf, 0, stateBytes, stream);
  for (int t = 0; t < T_SEQ; ++t) {
    lstm_step<<<(NHID + 15) / 16, 256, 0, stream>>>(
        xg, U1, hbuf + (size_t)(t & 1) * BATCH * NHID,
        hbuf + (size_t)((t + 1) & 1) * BATCH * NHID, cbuf, hB, NHID, t);
  }

  // ---- layer 2: 1150 -> 400 ----
  gemm_bias<<<dim3((4 * NINP + BN - 1) / BN, M / BM), 256, 0, stream>>>(
      hB, W2, b2, xg, M, 4 * NINP, NHID);
  hipMemsetAsync(hbuf, 0, stateBytes, stream);
  for (int t = 0; t < T_SEQ; ++t) {
    lstm_step<<<(NINP + 15) / 16, 256, 0, stream>>>(
        xg, U2, hbuf + (size_t)(t & 1) * BATCH * NINP,
        hbuf + (size_t)((t + 1) & 1) * BATCH * NINP, cbuf, hC, NINP, t);
  }

  // ---- decode + softmax ----
  gemm_bt<<<dim3((V + BN - 1) / BN, M / BM), 256, 0, stream>>>(hC, emb, out, M, V, NINP);
  softmax_kernel<<<M, 256, 0, stream>>>(out, V);
}